// Round 2
// baseline (959.658 us; speedup 1.0000x reference)
//
#include <hip/hip_runtime.h>
#include <hip/hip_bf16.h>
#include <type_traits>

// Problem constants (fixed shapes from setup_inputs)
constexpr int NB   = 4;      // batch
constexpr int SL   = 4096;   // sequence length
constexpr int DIMC = 1024;   // model dim
constexpr int NH   = 16;     // heads
constexpr int DHC  = 64;     // head dim
constexpr int NFC  = 64;     // random features
constexpr int NCH  = 16;     // L-chunks for partial N/D accumulation
constexpr int LC   = SL / NCH; // 256
constexpr float FEPS = 1e-6f;

typedef __attribute__((ext_vector_type(8))) short bf16x8_t;  // 8 bf16 (4 VGPRs)
typedef __attribute__((ext_vector_type(4))) float f32x4_t;   // MFMA accumulator
typedef __attribute__((ext_vector_type(4))) short s16x4_t;

__device__ __forceinline__ float rlane(float v, int i) {
  return __uint_as_float(__builtin_amdgcn_readlane(__float_as_uint(v), i));
}

// ---------------------------------------------------------------------------
// fp32 -> bf16 cast (n divisible by 1024). 4 elements/thread.
// ---------------------------------------------------------------------------
__global__ __launch_bounds__(256) void cast_f32_to_bf16(
    const float* __restrict__ in, short* __restrict__ out, int n)
{
  const int i = (blockIdx.x * 256 + threadIdx.x) * 4;
  if (i >= n) return;
  const f32x4_t v = *(const f32x4_t*)(in + i);
  s16x4_t o;
#pragma unroll
  for (int j = 0; j < 4; j++) {
    __hip_bfloat16 h = __float2bfloat16(v[j]);
    o[j] = *(short*)&h;
  }
  *(s16x4_t*)(out + i) = o;
}

// ---------------------------------------------------------------------------
// GEMM: C[M,1024] = A[M,1024] @ W[1024,1024]^T + bias  (bf16 MFMA, fp32 acc)
// A, W are bf16 (bit-pattern shorts); bias fp32; OutT = float or __hip_bfloat16
// wave = 64x64 tile (4x4 mfma frags), block = 4 waves = 128x128 tile
// grid: (M/128, 1024/128)
// ---------------------------------------------------------------------------
template <typename OutT>
__global__ __launch_bounds__(256) void gemm_bias_kernel(
    const short* __restrict__ A, const short* __restrict__ W,
    const float* __restrict__ bias, OutT* __restrict__ C)
{
  constexpr int K = 1024, N = 1024;
  const int lane = threadIdx.x & 63;
  const int wid  = threadIdx.x >> 6;
  const int sub  = lane & 15;
  const int quad = lane >> 4;
  const int row0 = blockIdx.x * 128 + (wid >> 1) * 64;
  const int col0 = blockIdx.y * 128 + (wid & 1) * 64;

  f32x4_t acc[4][4] = {};

  for (int k0 = 0; k0 < K; k0 += 32) {
    const int ka = k0 + quad * 8;
    bf16x8_t a[4], b[4];
#pragma unroll
    for (int i = 0; i < 4; i++)
      a[i] = *(const bf16x8_t*)(A + (size_t)(row0 + i * 16 + sub) * K + ka);
#pragma unroll
    for (int j = 0; j < 4; j++)
      b[j] = *(const bf16x8_t*)(W + (size_t)(col0 + j * 16 + sub) * K + ka);
#pragma unroll
    for (int i = 0; i < 4; i++)
#pragma unroll
      for (int j = 0; j < 4; j++)
        acc[i][j] = __builtin_amdgcn_mfma_f32_16x16x32_bf16(a[i], b[j], acc[i][j], 0, 0, 0);
  }

#pragma unroll
  for (int j = 0; j < 4; j++) {
    const int col = col0 + j * 16 + sub;
    const float bv = bias[col];
#pragma unroll
    for (int i = 0; i < 4; i++) {
      const int row = row0 + i * 16 + quad * 4;
#pragma unroll
      for (int r = 0; r < 4; r++) {
        const float val = acc[i][j][r] + bv;
        if constexpr (std::is_same_v<OutT, float>)
          C[(size_t)(row + r) * N + col] = val;
        else
          C[(size_t)(row + r) * N + col] = __float2bfloat16(val);
      }
    }
  }
}

// ---------------------------------------------------------------------------
// Key summary: per (b,h,chunk) accumulate unnormalized
//   w[l,f] = exp(k_l . W0[:,f] - 0.5*||k_l||^2)   (no max shift: logits are
//   ~ -32 +- 8; overflow would need logit > 88 ~ 13 sigma)
//   partialN[f,d] = sum_l w[l,f] * v[l,d],  partialD[f] = sum_l w[l,f]
// k fp32, v bf16, Wrf fp32. lane plays role f (logit/D) and role d (N).
// grid: (NCH, NH, NB), block 256 (4 waves; wave handles l = wid mod 4)
// ---------------------------------------------------------------------------
__global__ __launch_bounds__(256) void kv_summary_kernel(
    const float* __restrict__ kmat, const __hip_bfloat16* __restrict__ vmat,
    const float* __restrict__ Wrf,
    float* __restrict__ pN, float* __restrict__ pD)
{
  const int chunk = blockIdx.x, h = blockIdx.y, b = blockIdx.z;
  const int lane = threadIdx.x & 63, wid = threadIdx.x >> 6;

  float w0c[64];
#pragma unroll
  for (int d = 0; d < 64; d++)
    w0c[d] = Wrf[(h * DHC + d) * NFC + lane];  // W0[h][d][f=lane]

  float Nacc[64];
#pragma unroll
  for (int f = 0; f < 64; f++) Nacc[f] = 0.f;
  float Dacc = 0.f;

  const int l0 = chunk * LC;
  for (int li = wid; li < LC; li += 4) {
    const size_t base = ((size_t)(b * SL + l0 + li)) * DIMC + h * DHC;
    const float kl = kmat[base + lane];                    // k[l][d=lane]
    const float vl = __bfloat162float(vmat[base + lane]);  // v[l][d=lane]

    float ksq = kl * kl;
#pragma unroll
    for (int o = 32; o; o >>= 1) ksq += __shfl_xor(ksq, o);

    float lg = -0.5f * ksq;
#pragma unroll
    for (int d = 0; d < 64; d++) lg = fmaf(rlane(kl, d), w0c[d], lg);

    const float w = __expf(lg);   // w[l, f=lane]
    Dacc += w;
#pragma unroll
    for (int f = 0; f < 64; f++) Nacc[f] = fmaf(rlane(w, f), vl, Nacc[f]);
  }

  // block-level reduction of the 4 waves' Nacc via LDS, then one store
  __shared__ float red[4096];
  for (int t = threadIdx.x; t < 4096; t += 256) red[t] = 0.f;
  __syncthreads();
  for (int r = 0; r < 4; r++) {
    if (wid == r) {
#pragma unroll
      for (int f = 0; f < 64; f++) red[f * 64 + lane] += Nacc[f];
    }
    __syncthreads();
  }
  const size_t pbase = ((size_t)((b * NH + h) * NCH + chunk)) * 4096;
  for (int t = threadIdx.x; t < 4096; t += 256) pN[pbase + t] = red[t];

  __shared__ float dred[256];
  dred[threadIdx.x] = Dacc;
  __syncthreads();
  if (threadIdx.x < 64) {
    const float dsum = dred[threadIdx.x] + dred[64 + threadIdx.x] +
                       dred[128 + threadIdx.x] + dred[192 + threadIdx.x];
    pD[(size_t)((b * NH + h) * NCH + chunk) * 64 + threadIdx.x] = dsum;
  }
}

// ---------------------------------------------------------------------------
// Combine chunk partials, normalize by s = sum_f D[f] (softmax denominator).
// grid: (NB*NH), block 256
// ---------------------------------------------------------------------------
__global__ __launch_bounds__(256) void combine_nd_kernel(
    const float* __restrict__ pN, const float* __restrict__ pD,
    float* __restrict__ Nf, float* __restrict__ Df)
{
  const int bh = blockIdx.x;
  __shared__ float sInv;
  float dsum = 0.f;
  if (threadIdx.x < 64) {
    for (int c = 0; c < NCH; c++)
      dsum += pD[(size_t)(bh * NCH + c) * 64 + threadIdx.x];
    float s = dsum;
#pragma unroll
    for (int o = 32; o; o >>= 1) s += __shfl_xor(s, o);
    if (threadIdx.x == 0) sInv = 1.f / s;
  }
  __syncthreads();
  const float inv = sInv;
  if (threadIdx.x < 64) Df[bh * 64 + threadIdx.x] = dsum * inv;
  for (int t = threadIdx.x; t < 4096; t += 256) {
    float acc = 0.f;
    for (int c = 0; c < NCH; c++)
      acc += pN[((size_t)(bh * NCH + c)) * 4096 + t];
    Nf[(size_t)bh * 4096 + t] = acc * inv;
  }
}

// ---------------------------------------------------------------------------
// Query feature map + context: per (b,h,l):
//   phi = softmax_f(q . W0);  ctx[d] = (sum_f phi_f N[f,d]) / (sum_f phi_f D[f] + eps)
// q fp32 in, ctx bf16 out (feeds the bf16 output GEMM).
// grid: (NCH, NH, NB), block 256
// ---------------------------------------------------------------------------
__global__ __launch_bounds__(256) void query_ctx_kernel(
    const float* __restrict__ qmat, const float* __restrict__ Wrf,
    const float* __restrict__ Nf, const float* __restrict__ Df,
    __hip_bfloat16* __restrict__ ctx)
{
  const int chunk = blockIdx.x, h = blockIdx.y, b = blockIdx.z;
  const int lane = threadIdx.x & 63, wid = threadIdx.x >> 6;

  float w0c[64], Ncol[64];
#pragma unroll
  for (int d = 0; d < 64; d++)
    w0c[d] = Wrf[(h * DHC + d) * NFC + lane];
  const size_t nb = (size_t)(b * NH + h) * 4096;
#pragma unroll
  for (int f = 0; f < 64; f++) Ncol[f] = Nf[nb + f * 64 + lane];  // N[f][d=lane]
  const float Dl = Df[(b * NH + h) * 64 + lane];                   // D[f=lane]

  const int l0 = chunk * LC;
  for (int li = wid; li < LC; li += 4) {
    const size_t base = ((size_t)(b * SL + l0 + li)) * DIMC + h * DHC;
    const float ql = qmat[base + lane];  // q[l][d=lane]

    float lg = 0.f;
#pragma unroll
    for (int d = 0; d < 64; d++) lg = fmaf(rlane(ql, d), w0c[d], lg);  // qlogit[f=lane]

    float mx = lg;
#pragma unroll
    for (int o = 32; o; o >>= 1) mx = fmaxf(mx, __shfl_xor(mx, o));
    const float e = __expf(lg - mx);
    float se = e, dt = e * Dl;
#pragma unroll
    for (int o = 32; o; o >>= 1) { se += __shfl_xor(se, o); dt += __shfl_xor(dt, o); }

    float num = 0.f;
#pragma unroll
    for (int f = 0; f < 64; f++) num = fmaf(rlane(e, f), Ncol[f], num);  // role d

    const float den = dt / se;
    num /= se;
    ctx[base + lane] = __float2bfloat16(num / (den + FEPS));
  }
}

// ---------------------------------------------------------------------------
extern "C" void kernel_launch(void* const* d_in, const int* in_sizes, int n_in,
                              void* d_out, int out_size, void* d_ws, size_t ws_size,
                              hipStream_t stream) {
  (void)in_sizes; (void)n_in; (void)out_size; (void)ws_size;
  const float* x   = (const float*)d_in[0];
  const float* Wq  = (const float*)d_in[1];
  const float* bq  = (const float*)d_in[2];
  const float* Wk  = (const float*)d_in[3];
  const float* bk  = (const float*)d_in[4];
  const float* Wv  = (const float*)d_in[5];
  const float* bv  = (const float*)d_in[6];
  const float* Wo  = (const float*)d_in[7];
  const float* bo  = (const float*)d_in[8];
  const float* Wrf = (const float*)d_in[9];
  float* out = (float*)d_out;

  constexpr size_t MiB = 1u << 20;
  constexpr size_t NTOK = (size_t)NB * SL;            // 16384
  constexpr size_t XN   = NTOK * DIMC;                // 16,777,216 elements
  constexpr size_t WN   = (size_t)DIMC * DIMC;        // 1,048,576 elements

  char* ws = (char*)d_ws;
  short* xb  = (short*)(ws);                 // bf16 x, 32 MiB; reused as ctx later
  short* Wqb = (short*)(ws + 32 * MiB);      // 2 MiB each
  short* Wkb = (short*)(ws + 34 * MiB);
  short* Wvb = (short*)(ws + 36 * MiB);
  short* Wob = (short*)(ws + 38 * MiB);
  float* qb  = (float*)(ws + 40 * MiB);      // fp32 q, 64 MiB
  float* kb  = (float*)(ws + 104 * MiB);     // fp32 k, 64 MiB
  __hip_bfloat16* vb = (__hip_bfloat16*)(ws + 168 * MiB);  // bf16 v, 32 MiB
  float* pN  = (float*)(ws + 200 * MiB);     // 16 MiB
  float* pD  = (float*)(ws + 216 * MiB);     // 256 KiB
  float* Nf  = (float*)(ws + 217 * MiB);     // 1 MiB
  float* Df  = (float*)(ws + 218 * MiB);     // 16 KiB
  __hip_bfloat16* ctxb = (__hip_bfloat16*)xb;  // alias: xb dead after v GEMM

  const dim3 blk(256);

  // casts: fp32 -> bf16
  cast_f32_to_bf16<<<dim3(XN / 1024), blk, 0, stream>>>(x, xb, (int)XN);
  cast_f32_to_bf16<<<dim3(WN / 1024), blk, 0, stream>>>(Wq, Wqb, (int)WN);
  cast_f32_to_bf16<<<dim3(WN / 1024), blk, 0, stream>>>(Wk, Wkb, (int)WN);
  cast_f32_to_bf16<<<dim3(WN / 1024), blk, 0, stream>>>(Wv, Wvb, (int)WN);
  cast_f32_to_bf16<<<dim3(WN / 1024), blk, 0, stream>>>(Wo, Wob, (int)WN);

  const dim3 gg(NTOK / 128, DIMC / 128);
  gemm_bias_kernel<float><<<gg, blk, 0, stream>>>(xb, Wqb, bq, qb);
  gemm_bias_kernel<float><<<gg, blk, 0, stream>>>(xb, Wkb, bk, kb);
  gemm_bias_kernel<__hip_bfloat16><<<gg, blk, 0, stream>>>(xb, Wvb, bv, vb);

  kv_summary_kernel<<<dim3(NCH, NH, NB), blk, 0, stream>>>(kb, vb, Wrf, pN, pD);
  combine_nd_kernel<<<dim3(NB * NH), blk, 0, stream>>>(pN, pD, Nf, Df);
  query_ctx_kernel<<<dim3(NCH, NH, NB), blk, 0, stream>>>(qb, Wrf, Nf, Df, ctxb);

  gemm_bias_kernel<float><<<gg, blk, 0, stream>>>((const short*)ctxb, Wob, bo, out);
}